// Round 8
// baseline (447.095 us; speedup 1.0000x reference)
//
#include <hip/hip_runtime.h>
#include <cstdint>
#include <cstddef>

#define NFREQ 10
#define NN    65536
#define ENCD  42       // 2*(1+2*NFREQ)
#define K0    170      // ENCD + 128
#define S0    200      // h0 / W0t stride in fp16 elems (400B rows: 16B-aligned, 2-way banks)
#define S1    136      // hidden-layer stride (272B rows)
#define TM    128      // rows per block (8 waves x 16 rows, wave-private)
#define WSLICE 6400    // bytes per wave-private LDS slice (16 rows x S0 x 2B)

typedef _Float16 f16;
typedef f16  f16x8 __attribute__((ext_vector_type(8)));
typedef float f32x4 __attribute__((ext_vector_type(4)));

// ---- workspace layout (bytes) ----
#define WS_ENC   0u          // uint32 [24][NN] : packed fp16 pairs of enc (cols 2d,2d+1), transposed
#define WS_BILIN 6291456u    // float4 [NN] : {fy, fx, asfloat(y0), asfloat(x0)}
#define WS_W0T   7340032u    // f16 [128][S0]  rows=out, cols=in; in>=170 zeroed
#define WS_W1T   7391232u    // f16 [128][S1]
#define WS_W2T   7426048u    // f16 [128][S1]
#define WS_WOUT  7460864u    // f32 [4][128]   rows=out-col (row 3 zero)

// Epilogue tanh: R1-verbatim (proven numerics; 1 use/thread).
__device__ __forceinline__ float fast_tanh(float z) {
  z = fminf(fmaxf(z, -10.f), 10.f);           // avoid inf/inf
  float e = __expf(2.f * z);
  return (e - 1.f) * __builtin_amdgcn_rcpf(e + 1.f);
}
// gelu via sigmoid identity (R7-proven): ONE exp2 + ONE rcp, no NaN path.
__device__ __forceinline__ float gelu_fast(float x) {
  float z = 0.7978845608028654f * (x + 0.044715f * x * x * x);
  float e = __builtin_amdgcn_exp2f(-2.8853900817779268f * z);
  return x * __builtin_amdgcn_rcpf(1.f + e);
}

// ---------------- prep: posenc + bilinear params (R1-verbatim) ----------------
__global__ void prep_misc(const float* __restrict__ coords,
                          uint32_t* __restrict__ enc2, float4* __restrict__ bilin) {
  int n = blockIdx.x * blockDim.x + threadIdx.x;
  if (n >= NN) return;
  float cy = coords[2 * n + 0];
  float cx = coords[2 * n + 1];
  float e[48];
  e[0] = cy; e[1] = cx;
  float f = 3.14159265358979323846f;            // freqs[i] = 2^i * pi (exact doubling)
  #pragma unroll
  for (int i = 0; i < NFREQ; ++i) {
    float sy, cyv, sx, cxv;
    sincosf(cy * f, &sy, &cyv);
    sincosf(cx * f, &sx, &cxv);
    e[2 + 4 * i + 0] = sy;  e[2 + 4 * i + 1] = sx;
    e[2 + 4 * i + 2] = cyv; e[2 + 4 * i + 3] = cxv;
    f *= 2.0f;
  }
  #pragma unroll
  for (int k = ENCD; k < 48; ++k) e[k] = 0.f;
  #pragma unroll
  for (int d = 0; d < 24; ++d) {
    f16 lo = (f16)e[2 * d], hi = (f16)e[2 * d + 1];
    uint32_t u = (uint32_t)__builtin_bit_cast(uint16_t, lo) |
                 ((uint32_t)__builtin_bit_cast(uint16_t, hi) << 16);
    enc2[(size_t)d * NN + n] = u;
  }
  float ry = (cy + 1.f) * 0.5f * 63.f;
  float rx = (cx + 1.f) * 0.5f * 63.f;
  ry = fminf(fmaxf(ry, 0.f), 63.f);
  rx = fminf(fmaxf(rx, 0.f), 63.f);
  int y0 = min((int)ry, 62), x0 = min((int)rx, 62);
  bilin[n] = make_float4(ry - (float)y0, rx - (float)x0,
                         __int_as_float(y0), __int_as_float(x0));
}

// ---------------- prep: pack transposed fp16 weights (R1-verbatim) ----------------
__global__ void prep_w(const float* __restrict__ W0, const float* __restrict__ W1,
                       const float* __restrict__ W2, const float* __restrict__ Wo,
                       f16* __restrict__ w0t, f16* __restrict__ w1t,
                       f16* __restrict__ w2t, float* __restrict__ woutt) {
  int i = blockIdx.x * blockDim.x + threadIdx.x;
  const int n0 = 128 * S0, n1 = 128 * S1;
  if (i < n0) {
    int j = i / S0, k = i - j * S0;
    w0t[i] = (k < K0) ? (f16)W0[k * 128 + j] : (f16)0.f;
  } else if (i < n0 + n1) {
    int ii = i - n0; int j = ii / S1, k = ii - j * S1;
    w1t[ii] = (k < 128) ? (f16)W1[k * 128 + j] : (f16)0.f;
  } else if (i < n0 + 2 * n1) {
    int ii = i - n0 - n1; int j = ii / S1, k = ii - j * S1;
    w2t[ii] = (k < 128) ? (f16)W2[k * 128 + j] : (f16)0.f;
  } else if (i < n0 + 2 * n1 + 512) {
    int ii = i - n0 - 2 * n1; int oc = ii >> 7, k = ii & 127;
    woutt[ii] = (oc < 3) ? Wo[k * 3 + oc] : 0.f;
  }
}

// ---- half-layer: 4 n-blocks over full K, depth-1 register dbuf for B ----
template <int KSTEPS, int SS, int SW>
__device__ __forceinline__ void mlp_half(const f16* arow, const f16* __restrict__ wrow,
                                         f32x4 (&acc)[4]) {
  f16x8 bf[2][4];
  #pragma unroll
  for (int nb = 0; nb < 4; ++nb)
    bf[0][nb] = *(const f16x8*)(wrow + (16 * nb) * SW);
  #pragma unroll
  for (int kk = 0; kk < KSTEPS; ++kk) {
    if (kk + 1 < KSTEPS) {
      #pragma unroll
      for (int nb = 0; nb < 4; ++nb)
        bf[(kk + 1) & 1][nb] = *(const f16x8*)(wrow + (16 * nb) * SW + (kk + 1) * 32);
    }
    f16x8 a = *(const f16x8*)(arow + kk * 32);
    #pragma unroll
    for (int nb = 0; nb < 4; ++nb)
      acc[nb] = __builtin_amdgcn_mfma_f32_16x16x32_f16(a, bf[kk & 1][nb], acc[nb], 0, 0, 0);
  }
}

// ---- full layer for one wave: 16 rows x 128 cols, vals stay in regs ----
template <int KSTEPS, int SS, int SW>
__device__ __forceinline__ void mlp_full(const char* slice, const f16* __restrict__ wt,
                                         const float* __restrict__ bias,
                                         f16 (&vals)[8][4], int l15, int lk) {
  const f16* arow = (const f16*)slice + l15 * SS + 8 * lk;
  const f16* wrow = wt + l15 * SW + 8 * lk;
  f32x4 acc[8] = {};
  mlp_half<KSTEPS, SS, SW>(arow, wrow,            *(f32x4(*)[4])&acc[0]);
  mlp_half<KSTEPS, SS, SW>(arow, wrow + 64 * SW,  *(f32x4(*)[4])&acc[4]);
  #pragma unroll
  for (int nb = 0; nb < 8; ++nb) {
    float bv = bias[16 * nb + l15];
    #pragma unroll
    for (int r = 0; r < 4; ++r)
      vals[nb][r] = (f16)gelu_fast(acc[nb][r] + bv);
  }
}

// ---- store wave's 16x128 activations into its slice (C/D: col=l&15, row=4*lk+r) ----
template <int SD>
__device__ __forceinline__ void store_h(char* slice, const f16 (&vals)[8][4], int l15, int lk) {
  f16* h = (f16*)slice;
  #pragma unroll
  for (int nb = 0; nb < 8; ++nb)
    #pragma unroll
    for (int r = 0; r < 4; ++r)
      h[(4 * lk + r) * SD + 16 * nb + l15] = vals[nb][r];
}

// ---------------- main kernel: ZERO barriers; wave-private 16-row pipelines ----------------
__global__ __launch_bounds__(512, 4) void decoder_main(
    const float* __restrict__ fg, const uint32_t* __restrict__ enc2,
    const float4* __restrict__ bilin,
    const f16* __restrict__ w0t, const f16* __restrict__ w1t, const f16* __restrict__ w2t,
    const float* __restrict__ woutt,
    const float* __restrict__ b0, const float* __restrict__ b1, const float* __restrict__ b2,
    const float* __restrict__ bout, float* __restrict__ out) {
  __shared__ __align__(16) unsigned char smem[8 * WSLICE];   // 51,200 B

  const int tid  = threadIdx.x;
  const int lane = tid & 63, wv = tid >> 6;
  const int l15  = lane & 15, lk = lane >> 4;
  const int bid  = blockIdx.x;
  const int b    = bid >> 9;
  const int n0   = (bid & 511) * TM;
  const int r0   = n0 + 16 * wv;                 // wave's first global row
  char* slice = (char*)smem + wv * WSLICE;

  // ---- phase 0 (wave-private): h0 rows = [enc(42) | sampled(128) | zeros(30)] ----
  for (int i = lane; i < 21 * 16; i += 64) {     // enc dwords 0..20 for 16 rows
    int d = i >> 4, j = i & 15;
    *(uint32_t*)(slice + j * 400 + 4 * d) = enc2[(size_t)d * NN + r0 + j];
  }
  for (int i = lane; i < 15 * 16; i += 64) {     // zero dwords 85..99 (cols 170..199)
    int d = i >> 4, j = i & 15;
    *(uint32_t*)(slice + j * 400 + 4 * (85 + d)) = 0u;
  }
  {
    const float* base = fg + (size_t)b * (64 * 64 * 128);
    #pragma unroll 4
    for (int j = 0; j < 16; ++j) {               // wave's 16 rows; lanes = 2 channels each
      float4 p  = bilin[r0 + j];
      float fy = p.x, fx = p.y;
      int y0 = __float_as_int(p.z), x0 = __float_as_int(p.w);
      int y1 = min(y0 + 1, 63), x1 = min(x0 + 1, 63);
      const float2* v00 = (const float2*)(base + (y0 * 64 + x0) * 128) + lane;
      const float2* v01 = (const float2*)(base + (y0 * 64 + x1) * 128) + lane;
      const float2* v10 = (const float2*)(base + (y1 * 64 + x0) * 128) + lane;
      const float2* v11 = (const float2*)(base + (y1 * 64 + x1) * 128) + lane;
      float w00 = (1.f - fy) * (1.f - fx), w01 = (1.f - fy) * fx;
      float w10 = fy * (1.f - fx),         w11 = fy * fx;
      float2 a = *v00, c = *v01, d2 = *v10, e2 = *v11;
      float s0 = a.x * w00 + c.x * w01 + d2.x * w10 + e2.x * w11;
      float s1 = a.y * w00 + c.y * w01 + d2.y * w10 + e2.y * w11;
      f16 q0 = (f16)s0, q1 = (f16)s1;
      uint32_t u = (uint32_t)__builtin_bit_cast(uint16_t, q0) |
                   ((uint32_t)__builtin_bit_cast(uint16_t, q1) << 16);
      *(uint32_t*)(slice + j * 400 + 84 + 4 * lane) = u;   // cols 42+2*lane
    }
  }
  // no __syncthreads anywhere: slice is wave-private; in-wave LDS ordering via lgkmcnt

  f16 v[8][4];
  mlp_full<6, S0, S0>(slice, w0t, b0, v, l15, lk);   // L0 reads h0 (K=192 incl. zero pad)
  store_h<S1>(slice, v, l15, lk);                    // h1 overwrites h0
  mlp_full<4, S1, S1>(slice, w1t, b1, v, l15, lk);   // L1
  store_h<S1>(slice, v, l15, lk);                    // h2
  mlp_full<4, S1, S1>(slice, w2t, b2, v, l15, lk);   // L2
  store_h<S1>(slice, v, l15, lk);                    // h3

  // ---- output layer (wave-private): lane = 4*rowLocal + oc, oc==3 dummy ----
  {
    int row = lane >> 2, oc = lane & 3;
    const f16*  hr = (const f16*)slice + row * S1;
    const float* wr = woutt + oc * 128;
    float acc = 0.f;
    #pragma unroll
    for (int i = 0; i < 16; ++i) {
      f16x8 hv = *(const f16x8*)(hr + 8 * i);
      float4 wa = *(const float4*)(wr + 8 * i);
      float4 wb = *(const float4*)(wr + 8 * i + 4);
      acc += (float)hv[0] * wa.x + (float)hv[1] * wa.y + (float)hv[2] * wa.z + (float)hv[3] * wa.w
           + (float)hv[4] * wb.x + (float)hv[5] * wb.y + (float)hv[6] * wb.z + (float)hv[7] * wb.w;
    }
    if (oc < 3)
      out[((size_t)b * NN + r0 + row) * 3 + oc] = fast_tanh(acc + bout[oc]);
  }
}

extern "C" void kernel_launch(void* const* d_in, const int* in_sizes, int n_in,
                              void* d_out, int out_size, void* d_ws, size_t ws_size,
                              hipStream_t stream) {
  const float* fg     = (const float*)d_in[0];
  const float* coords = (const float*)d_in[1];
  const float* W0 = (const float*)d_in[2]; const float* b0 = (const float*)d_in[3];
  const float* W1 = (const float*)d_in[4]; const float* b1 = (const float*)d_in[5];
  const float* W2 = (const float*)d_in[6]; const float* b2 = (const float*)d_in[7];
  const float* Wo = (const float*)d_in[8]; const float* bo = (const float*)d_in[9];
  char* ws = (char*)d_ws;
  uint32_t* enc2  = (uint32_t*)(ws + WS_ENC);
  float4*   bilin = (float4*)(ws + WS_BILIN);
  f16* w0t = (f16*)(ws + WS_W0T);
  f16* w1t = (f16*)(ws + WS_W1T);
  f16* w2t = (f16*)(ws + WS_W2T);
  float* woutt = (float*)(ws + WS_WOUT);

  prep_misc<<<256, 256, 0, stream>>>(coords, enc2, bilin);
  int prep_items = 128 * S0 + 2 * 128 * S1 + 512;
  prep_w<<<(prep_items + 255) / 256, 256, 0, stream>>>(W0, W1, W2, Wo, w0t, w1t, w2t, woutt);
  decoder_main<<<4096, 512, 0, stream>>>(fg, enc2, bilin, w0t, w1t, w2t, woutt,
      b0, b1, b2, bo, (float*)d_out);
}

// Round 9
// 382.984 us; speedup vs baseline: 1.1674x; 1.1674x over previous
//
#include <hip/hip_runtime.h>
#include <cstdint>
#include <cstddef>

#define NFREQ 10
#define NN    65536
#define ENCD  42       // 2*(1+2*NFREQ)
#define K0    170      // ENCD + 128
#define S0    200      // h0 / W0t stride in fp16 elems (400B rows: 16B-aligned, 2-way banks)
#define S1    136      // hidden-layer stride (272B rows)
#define TM    128      // rows per block

typedef _Float16 f16;
typedef f16  f16x8 __attribute__((ext_vector_type(8)));
typedef float f32x4 __attribute__((ext_vector_type(4)));

// ---- workspace layout (bytes) ----
#define WS_ENC   0u          // uint32 [24][NN] : packed fp16 pairs of enc (cols 2d,2d+1), transposed
#define WS_BILIN 6291456u    // float4 [NN] : {fy, fx, asfloat(y0), asfloat(x0)}
#define WS_W0T   7340032u    // f16 [128][S0]  rows=out, cols=in; in>=170 zeroed
#define WS_W1T   7391232u    // f16 [128][S1]
#define WS_W2T   7426048u    // f16 [128][S1]
#define WS_WOUT  7460864u    // f32 [4][128]   rows=out-col (row 3 zero)

// Epilogue tanh: R1-verbatim (proven numerics; only 384 threads use it).
__device__ __forceinline__ float fast_tanh(float z) {
  z = fminf(fmaxf(z, -10.f), 10.f);           // avoid inf/inf
  float e = __expf(2.f * z);
  return (e - 1.f) * __builtin_amdgcn_rcpf(e + 1.f);
}
// gelu via sigmoid identity (R7-proven): ONE exp2 + ONE rcp, no NaN path.
__device__ __forceinline__ float gelu_fast(float x) {
  float z = 0.7978845608028654f * (x + 0.044715f * x * x * x);
  float e = __builtin_amdgcn_exp2f(-2.8853900817779268f * z);
  return x * __builtin_amdgcn_rcpf(1.f + e);
}

// ---------------- prep: posenc + bilinear params (R1-verbatim) ----------------
__global__ void prep_misc(const float* __restrict__ coords,
                          uint32_t* __restrict__ enc2, float4* __restrict__ bilin) {
  int n = blockIdx.x * blockDim.x + threadIdx.x;
  if (n >= NN) return;
  float cy = coords[2 * n + 0];
  float cx = coords[2 * n + 1];
  float e[48];
  e[0] = cy; e[1] = cx;
  float f = 3.14159265358979323846f;            // freqs[i] = 2^i * pi (exact doubling)
  #pragma unroll
  for (int i = 0; i < NFREQ; ++i) {
    float sy, cyv, sx, cxv;
    sincosf(cy * f, &sy, &cyv);
    sincosf(cx * f, &sx, &cxv);
    e[2 + 4 * i + 0] = sy;  e[2 + 4 * i + 1] = sx;
    e[2 + 4 * i + 2] = cyv; e[2 + 4 * i + 3] = cxv;
    f *= 2.0f;
  }
  #pragma unroll
  for (int k = ENCD; k < 48; ++k) e[k] = 0.f;
  #pragma unroll
  for (int d = 0; d < 24; ++d) {
    f16 lo = (f16)e[2 * d], hi = (f16)e[2 * d + 1];
    uint32_t u = (uint32_t)__builtin_bit_cast(uint16_t, lo) |
                 ((uint32_t)__builtin_bit_cast(uint16_t, hi) << 16);
    enc2[(size_t)d * NN + n] = u;
  }
  float ry = (cy + 1.f) * 0.5f * 63.f;
  float rx = (cx + 1.f) * 0.5f * 63.f;
  ry = fminf(fmaxf(ry, 0.f), 63.f);
  rx = fminf(fmaxf(rx, 0.f), 63.f);
  int y0 = min((int)ry, 62), x0 = min((int)rx, 62);
  bilin[n] = make_float4(ry - (float)y0, rx - (float)x0,
                         __int_as_float(y0), __int_as_float(x0));
}

// ---------------- prep: pack transposed fp16 weights (R1-verbatim) ----------------
__global__ void prep_w(const float* __restrict__ W0, const float* __restrict__ W1,
                       const float* __restrict__ W2, const float* __restrict__ Wo,
                       f16* __restrict__ w0t, f16* __restrict__ w1t,
                       f16* __restrict__ w2t, float* __restrict__ woutt) {
  int i = blockIdx.x * blockDim.x + threadIdx.x;
  const int n0 = 128 * S0, n1 = 128 * S1;
  if (i < n0) {
    int j = i / S0, k = i - j * S0;
    w0t[i] = (k < K0) ? (f16)W0[k * 128 + j] : (f16)0.f;
  } else if (i < n0 + n1) {
    int ii = i - n0; int j = ii / S1, k = ii - j * S1;
    w1t[ii] = (k < 128) ? (f16)W1[k * 128 + j] : (f16)0.f;
  } else if (i < n0 + 2 * n1) {
    int ii = i - n0 - n1; int j = ii / S1, k = ii - j * S1;
    w2t[ii] = (k < 128) ? (f16)W2[k * 128 + j] : (f16)0.f;
  } else if (i < n0 + 2 * n1 + 512) {
    int ii = i - n0 - 2 * n1; int oc = ii >> 7, k = ii & 127;
    woutt[ii] = (oc < 3) ? Wo[k * 3 + oc] : 0.f;
  }
}

// ---- K-chunk: batch-load ALL B fragments (static reg array), then MFMA ----
// One L2 latency exposure per chunk instead of one per kk (R7's serial chain).
template <int KS0, int KCHUNK, int SS, int SW>
__device__ __forceinline__ void mlp_chunk(const f16* arow0, const f16* arow1,
                                          const f16* __restrict__ wrow,
                                          f32x4 (&acc)[2][4]) {
  f16x8 bf[KCHUNK][4];
  #pragma unroll
  for (int kk = 0; kk < KCHUNK; ++kk)
    #pragma unroll
    for (int ns = 0; ns < 4; ++ns)
      bf[kk][ns] = *(const f16x8*)(wrow + (16 * ns) * SW + (KS0 + kk) * 32);
  #pragma unroll
  for (int kk = 0; kk < KCHUNK; ++kk) {
    f16x8 a0 = *(const f16x8*)(arow0 + (KS0 + kk) * 32);
    f16x8 a1 = *(const f16x8*)(arow1 + (KS0 + kk) * 32);
    #pragma unroll
    for (int ns = 0; ns < 4; ++ns) {
      acc[0][ns] = __builtin_amdgcn_mfma_f32_16x16x32_f16(a0, bf[kk][ns], acc[0][ns], 0, 0, 0);
      acc[1][ns] = __builtin_amdgcn_mfma_f32_16x16x32_f16(a1, bf[kk][ns], acc[1][ns], 0, 0, 0);
    }
  }
}

template <int SS, int SW, int NCHUNK>   // NCHUNK K-chunks of 3 or full-4
__device__ __forceinline__ void mlp_compute(const f16* hsrc,
                                            const f16* __restrict__ wt,
                                            const float* __restrict__ bias,
                                            f16 (&vals)[2][4][4],
                                            int mg, int ng, int l15, int lk) {
  f32x4 acc[2][4] = {};
  const f16* wrow  = wt + (64 * ng + l15) * SW + 8 * lk;
  const f16* arow0 = hsrc + (32 * mg +      l15) * SS + 8 * lk;
  const f16* arow1 = hsrc + (32 * mg + 16 + l15) * SS + 8 * lk;
  if constexpr (NCHUNK == 2) {          // L0: K=192 as 3+3
    mlp_chunk<0, 3, SS, SW>(arow0, arow1, wrow, acc);
    mlp_chunk<3, 3, SS, SW>(arow0, arow1, wrow, acc);
  } else {                              // L1/L2: K=128 in one batch (64 B-VGPR)
    mlp_chunk<0, 4, SS, SW>(arow0, arow1, wrow, acc);
  }
  #pragma unroll
  for (int ms = 0; ms < 2; ++ms)
    #pragma unroll
    for (int ns = 0; ns < 4; ++ns) {
      int col = 64 * ng + 16 * ns + l15;
      float bv = bias[col];
      #pragma unroll
      for (int r = 0; r < 4; ++r)
        vals[ms][ns][r] = (f16)gelu_fast(acc[ms][ns][r] + bv);
    }
}

__device__ __forceinline__ void mlp_store(const f16 (&vals)[2][4][4], f16* hdst, int sD,
                                          int mg, int ng, int l15, int lk) {
  #pragma unroll
  for (int ms = 0; ms < 2; ++ms)
    #pragma unroll
    for (int ns = 0; ns < 4; ++ns) {
      int col = 64 * ng + 16 * ns + l15;
      #pragma unroll
      for (int r = 0; r < 4; ++r) {
        int row = 32 * mg + 16 * ms + 4 * lk + r;     // C/D: col=lane&15, row=4*(lane>>4)+reg
        hdst[row * sD + col] = vals[ms][ns][r];
      }
    }
}

// ---------------- main fused kernel: 68KB LDS overlay, 2 WG/CU (R6/R7 structure) ----------------
__global__ __launch_bounds__(512, 4) void decoder_main(
    const float* __restrict__ fg, const uint32_t* __restrict__ enc2,
    const float4* __restrict__ bilin,
    const f16* __restrict__ w0t, const f16* __restrict__ w1t, const f16* __restrict__ w2t,
    const float* __restrict__ woutt,
    const float* __restrict__ b0, const float* __restrict__ b1, const float* __restrict__ b2,
    const float* __restrict__ bout, float* __restrict__ out) {
  __shared__ __align__(16) unsigned char smem[69632];
  f16* hA = (f16*)smem;                   // h0 (stride S0, 51200B) -> h1 (stride S1) -> h3
  f16* hB = (f16*)(smem + 34816);         // h2 (stride S1)

  const int tid  = threadIdx.x;
  const int lane = tid & 63, wv = tid >> 6;
  const int l15  = lane & 15, lk = lane >> 4;
  const int mg   = wv & 3,    ng = wv >> 2;
  const int bid  = blockIdx.x;
  const int b    = bid >> 9;
  const int n0   = (bid & 511) * TM;

  // ---- phase 0: build h0 = [enc(42) | sampled(128) | zeros(30)] fp16 (R5-verbatim) ----
  for (int i = tid; i < 128 * 21; i += 512) {           // enc cols 0..41 (21 dwords/row)
    int d = i >> 7, r = i & 127;
    ((uint32_t*)((char*)hA + r * 400))[d] = enc2[(size_t)d * NN + n0 + r];
  }
  for (int i = tid; i < 128 * 16; i += 512) {           // zero cols 170..199 (dwords 85..99)
    int d = i & 15, r = i >> 4;
    if (d < 15) ((uint32_t*)((char*)hA + r * 400))[85 + d] = 0u;
  }
  {
    const float* base = fg + (size_t)b * (64 * 64 * 128);
    #pragma unroll 4
    for (int j = 0; j < 16; ++j) {                      // each wave: 16 rows; lanes = 2 channels each
      int r = wv + 8 * j;
      float4 p  = bilin[n0 + r];
      float fy = p.x, fx = p.y;
      int y0 = __float_as_int(p.z), x0 = __float_as_int(p.w);
      int y1 = min(y0 + 1, 63), x1 = min(x0 + 1, 63);
      const float2* v00 = (const float2*)(base + (y0 * 64 + x0) * 128) + lane;
      const float2* v01 = (const float2*)(base + (y0 * 64 + x1) * 128) + lane;
      const float2* v10 = (const float2*)(base + (y1 * 64 + x0) * 128) + lane;
      const float2* v11 = (const float2*)(base + (y1 * 64 + x1) * 128) + lane;
      float w00 = (1.f - fy) * (1.f - fx), w01 = (1.f - fy) * fx;
      float w10 = fy * (1.f - fx),         w11 = fy * fx;
      float2 a = *v00, c = *v01, d2 = *v10, e2 = *v11;
      float s0 = a.x * w00 + c.x * w01 + d2.x * w10 + e2.x * w11;
      float s1 = a.y * w00 + c.y * w01 + d2.y * w10 + e2.y * w11;
      f16 q0 = (f16)s0, q1 = (f16)s1;
      uint32_t u = (uint32_t)__builtin_bit_cast(uint16_t, q0) |
                   ((uint32_t)__builtin_bit_cast(uint16_t, q1) << 16);
      *(uint32_t*)((char*)hA + r * 400 + 84 + 4 * lane) = u;   // cols 42+2*lane
    }
  }
  __syncthreads();

  f16 v[2][4][4];
  // L0: K=192(pad); defer store — h1 overlays h0 after the read barrier
  mlp_compute<S0, S0, 2>(hA, w0t, b0, v, mg, ng, l15, lk);
  __syncthreads();                                   // all h0 reads done
  mlp_store(v, hA, S1, mg, ng, l15, lk);             // h1 -> [0,34816)
  __syncthreads();
  // L1: h1 -> h2 (disjoint regions, direct store)
  mlp_compute<S1, S1, 1>(hA, w1t, b1, v, mg, ng, l15, lk);
  mlp_store(v, hB, S1, mg, ng, l15, lk);             // h2 -> [34816,69632)
  __syncthreads();
  // L2: h2 -> h3 (h1 region is dead, direct store)
  mlp_compute<S1, S1, 1>(hB, w2t, b2, v, mg, ng, l15, lk);
  mlp_store(v, hA, S1, mg, ng, l15, lk);             // h3 -> [0,34816)
  __syncthreads();

  // ---- output layer: 128x3, fp32 vector, coalesced store (R5-verbatim, src=hA) ----
  if (tid < 384) {
    int row = tid / 3, oc = tid - 3 * row;
    const f16*  hr = hA + row * S1;
    const float* wr = woutt + oc * 128;
    float acc = 0.f;
    #pragma unroll
    for (int i = 0; i < 16; ++i) {
      f16x8 hv = *(const f16x8*)(hr + 8 * i);
      float4 wa = *(const float4*)(wr + 8 * i);
      float4 wb = *(const float4*)(wr + 8 * i + 4);
      acc += (float)hv[0] * wa.x + (float)hv[1] * wa.y + (float)hv[2] * wa.z + (float)hv[3] * wa.w
           + (float)hv[4] * wb.x + (float)hv[5] * wb.y + (float)hv[6] * wb.z + (float)hv[7] * wb.w;
    }
    out[((size_t)b * NN + n0 + row) * 3 + oc] = fast_tanh(acc + bout[oc]);
  }
}

extern "C" void kernel_launch(void* const* d_in, const int* in_sizes, int n_in,
                              void* d_out, int out_size, void* d_ws, size_t ws_size,
                              hipStream_t stream) {
  const float* fg     = (const float*)d_in[0];
  const float* coords = (const float*)d_in[1];
  const float* W0 = (const float*)d_in[2]; const float* b0 = (const float*)d_in[3];
  const float* W1 = (const float*)d_in[4]; const float* b1 = (const float*)d_in[5];
  const float* W2 = (const float*)d_in[6]; const float* b2 = (const float*)d_in[7];
  const float* Wo = (const float*)d_in[8]; const float* bo = (const float*)d_in[9];
  char* ws = (char*)d_ws;
  uint32_t* enc2  = (uint32_t*)(ws + WS_ENC);
  float4*   bilin = (float4*)(ws + WS_BILIN);
  f16* w0t = (f16*)(ws + WS_W0T);
  f16* w1t = (f16*)(ws + WS_W1T);
  f16* w2t = (f16*)(ws + WS_W2T);
  float* woutt = (float*)(ws + WS_WOUT);

  prep_misc<<<256, 256, 0, stream>>>(coords, enc2, bilin);
  int prep_items = 128 * S0 + 2 * 128 * S1 + 512;
  prep_w<<<(prep_items + 255) / 256, 256, 0, stream>>>(W0, W1, W2, Wo, w0t, w1t, w2t, woutt);
  decoder_main<<<4096, 512, 0, stream>>>(fg, enc2, bilin, w0t, w1t, w2t, woutt,
      b0, b1, b2, bo, (float*)d_out);
}